// Round 7
// baseline (120.744 us; speedup 1.0000x reference)
//
#include <hip/hip_runtime.h>
#include <cstddef>

// Problem constants
#define P_TOTAL 32768            // keys (32 images x 32 x 32)
#define Q_TOTAL 4096             // queries (4 x 32 x 32)
#define NSPLIT 128               // key splits
#define KPS 256                  // keys per split
#define TILES 16                 // 16-key MFMA tiles per split
#define QPERWG 256               // queries per workgroup (4 waves x 64)
#define NQG (Q_TOTAL / QPERWG)   // 16 query groups
#define GRID (NSPLIT * NQG)      // 2048 workgroups

typedef _Float16 half8 __attribute__((ext_vector_type(8)));
typedef float floatx4 __attribute__((ext_vector_type(4)));
typedef float floatx2 __attribute__((ext_vector_type(2)));

__device__ __forceinline__ float fexp2(float x) {
#if defined(__has_builtin) && __has_builtin(__builtin_amdgcn_exp2f)
    return __builtin_amdgcn_exp2f(x);
#else
    return exp2f(x);
#endif
}

// ---------------------------------------------------------------------------
// Kernel 1: q16[Q][32] f16 query rows (27 patch vals, 1.0 bias-mate, zeros).
// ---------------------------------------------------------------------------
__global__ __launch_bounds__(256) void qbuild_k(
    const float* __restrict__ x, _Float16* __restrict__ q16)
{
    int q = blockIdx.x * 256 + threadIdx.x;   // 0..4095
    int b = q >> 10, rem = q & 1023, h = rem >> 5, w = rem & 31;
    const float* xb = x + (size_t)b * 3072;
    _Float16 row[32];
    #pragma unroll
    for (int c = 0; c < 3; c++)
      #pragma unroll
      for (int di = 0; di < 3; di++)
        #pragma unroll
        for (int dj = 0; dj < 3; dj++)
            row[c * 9 + di * 3 + dj] =
                (_Float16)xb[c * 1024 + ((h + di + 31) & 31) * 32 + ((w + dj + 31) & 31)];
    row[27] = (_Float16)1.0f;
    row[28] = (_Float16)0.f; row[29] = (_Float16)0.f;
    row[30] = (_Float16)0.f; row[31] = (_Float16)0.f;
    _Float16* qp = q16 + (size_t)q * 32;
    #pragma unroll
    for (int u = 0; u < 4; u++) ((float4*)qp)[u] = ((float4*)row)[u];
}

// ---------------------------------------------------------------------------
// Kernel 2: fused key-build + flash scorer, keys-in-A orientation.
// mfma(A=key tile, B=queries, C): D[m=key=quad*4+reg][n=query=lane&15].
// NSPLIT=128/KPS=256: LDS 19.4 KB -> 8 wg/CU resident (vs 4 in R6).
// Packed-f32 accumulate: keys r={0,1} and r={2,3} live in the halves of
// float2 accumulators -> v_pk_fma_f32/v_pk_max_f32 (gfx90a+), horizontal
// fold once at the end. Centers in 3 SoA float planes (3 KB LDS): per tile
// one phase-uniform (broadcast) ds_read_b128 per plane, no f16 cvt.
// Pass 1: per-lane pk-max. Pass 2: exact -m folded into MFMA C operand.
// ---------------------------------------------------------------------------
__global__ __launch_bounds__(256) void score_k(
    const _Float16* __restrict__ q16, const float* __restrict__ images,
    const float* __restrict__ mu_sched, const float* __restrict__ sigma_sched,
    const int* __restrict__ tptr, float* __restrict__ partials)
{
    __shared__ char lds[KPS * 64 + 3 * KPS * 4];   // keys 16 KB + 3 ctr planes 3 KB
    float* ctrp = (float*)(lds + KPS * 64);        // ctrp[plane*KPS + row]
    int tid = threadIdx.x;
    int split = blockIdx.x >> 4;     // 0..127
    int qg    = blockIdx.x & 15;     // 0..15

    int t = tptr[0];
    float mu = mu_sched[t], sg = sigma_sched[t];
    const float LOG2E = 1.4426950408889634f;
    float inv2s2 = 1.0f / (2.0f * sg * sg);
    float s1     = 2.0f * mu * inv2s2 * LOG2E;   // key value scale
    float bscale = -mu * mu * inv2s2 * LOG2E;    // pnorm bias scale

    // ---- Phase 1: build this split's 256 keys into LDS (1 per thread) ----
    {
        int r = tid;                             // LDS key row 0..255
        int p = split * KPS + r;                 // global key id
        int n = p >> 10, rem = p & 1023, i = rem >> 5, j = rem & 31;
        const float* img = images + (size_t)n * 3072;
        _Float16 hrow[32];
        float pnorm = 0.f, c0 = 0.f, c1 = 0.f, c2 = 0.f;
        #pragma unroll
        for (int c = 0; c < 3; c++)
          #pragma unroll
          for (int di = 0; di < 3; di++)
            #pragma unroll
            for (int dj = 0; dj < 3; dj++) {
                int ii = i + di - 1, jj = j + dj - 1;
                float val = 0.f;
                if (ii >= 0 && ii < 32 && jj >= 0 && jj < 32)
                    val = img[c * 1024 + ii * 32 + jj];
                hrow[c * 9 + di * 3 + dj] = (_Float16)(val * s1);
                pnorm = fmaf(val, val, pnorm);
                if (di == 1 && dj == 1) { if (c == 0) c0 = val; else if (c == 1) c1 = val; else c2 = val; }
            }
        hrow[27] = (_Float16)(pnorm * bscale);
        hrow[28] = (_Float16)0.f; hrow[29] = (_Float16)0.f;
        hrow[30] = (_Float16)0.f; hrow[31] = (_Float16)0.f;
        int sw = (r >> 1) & 3;                   // 16B-chunk XOR swizzle
        float4* src4 = (float4*)hrow;
        #pragma unroll
        for (int c = 0; c < 4; c++)
            *(float4*)(lds + r * 64 + ((c ^ sw) << 4)) = src4[c];
        ctrp[0 * KPS + r] = c0;
        ctrp[1 * KPS + r] = c1;
        ctrp[2 * KPS + r] = c2;
    }

    // ---- B-fragments: queries from q16 (global, L2-hot) ----
    int lane = tid & 63, wid = tid >> 6;
    int col  = lane & 15, quad = lane >> 4;
    int qbase = qg * QPERWG + wid * 64;

    half8 qf[4];
    #pragma unroll
    for (int f = 0; f < 4; f++)
        qf[f] = *(const half8*)(q16 + (size_t)(qbase + f * 16 + col) * 32 + quad * 8);
    __syncthreads();

    int swc = (col >> 1) & 3;
    const char* abase = lds + col * 64 + ((quad ^ swc) << 4);   // key row = tile*16+col

    // ---- Pass 1: per-lane packed max over this lane's keys ----
    floatx2 mx2[4];
    #pragma unroll
    for (int f = 0; f < 4; f++) mx2[f] = (floatx2){-3e38f, -3e38f};
    {
        #pragma unroll 4
        for (int tile = 0; tile < TILES; tile++) {
            half8 ak = *(const half8*)(abase + tile * 1024);
            #pragma unroll
            for (int f = 0; f < 4; f++) {
                floatx4 a = __builtin_amdgcn_mfma_f32_16x16x32_f16(
                    ak, qf[f], (floatx4){0.f, 0.f, 0.f, 0.f}, 0, 0, 0);
                floatx2 alo = __builtin_shufflevector(a, a, 0, 1);
                floatx2 ahi = __builtin_shufflevector(a, a, 2, 3);
                mx2[f] = __builtin_elementwise_max(
                    mx2[f], __builtin_elementwise_max(alo, ahi));
            }
        }
    }
    float mx[4];
    #pragma unroll
    for (int f = 0; f < 4; f++) {
        mx[f] = fmaxf(mx2[f].x, mx2[f].y);
        mx[f] = fmaxf(mx[f], __shfl_xor(mx[f], 16, 64));
        mx[f] = fmaxf(mx[f], __shfl_xor(mx[f], 32, 64));
    }
    floatx4 nmv[4];
    #pragma unroll
    for (int f = 0; f < 4; f++)
        nmv[f] = (floatx4){-mx[f], -mx[f], -mx[f], -mx[f]};

    // ---- Pass 2: exp2 (exact -m in C) + packed accumulate ----
    floatx2 sv2[4], w02[4], w12[4], w22[4];
    #pragma unroll
    for (int f = 0; f < 4; f++) {
        sv2[f] = (floatx2){0.f, 0.f};
        w02[f] = sv2[f]; w12[f] = sv2[f]; w22[f] = sv2[f];
    }
    {
        #pragma unroll 2
        for (int tile = 0; tile < TILES; tile++) {
            half8 ak = *(const half8*)(abase + tile * 1024);
            int gr = tile * 16 + quad * 4;       // this lane's 4 key rows
            floatx4 c0q = *(const floatx4*)(ctrp + 0 * KPS + gr);  // broadcast reads
            floatx4 c1q = *(const floatx4*)(ctrp + 1 * KPS + gr);
            floatx4 c2q = *(const floatx4*)(ctrp + 2 * KPS + gr);
            floatx2 c0a = __builtin_shufflevector(c0q, c0q, 0, 1);
            floatx2 c0b = __builtin_shufflevector(c0q, c0q, 2, 3);
            floatx2 c1a = __builtin_shufflevector(c1q, c1q, 0, 1);
            floatx2 c1b = __builtin_shufflevector(c1q, c1q, 2, 3);
            floatx2 c2a = __builtin_shufflevector(c2q, c2q, 0, 1);
            floatx2 c2b = __builtin_shufflevector(c2q, c2q, 2, 3);
            #pragma unroll
            for (int f = 0; f < 4; f++) {
                floatx4 a = __builtin_amdgcn_mfma_f32_16x16x32_f16(ak, qf[f], nmv[f], 0, 0, 0);
                floatx2 e01 = {fexp2(a[0]), fexp2(a[1])};
                floatx2 e23 = {fexp2(a[2]), fexp2(a[3])};
                sv2[f] += e01 + e23;
                w02[f] = __builtin_elementwise_fma(e01, c0a, w02[f]);
                w02[f] = __builtin_elementwise_fma(e23, c0b, w02[f]);
                w12[f] = __builtin_elementwise_fma(e01, c1a, w12[f]);
                w12[f] = __builtin_elementwise_fma(e23, c1b, w12[f]);
                w22[f] = __builtin_elementwise_fma(e01, c2a, w22[f]);
                w22[f] = __builtin_elementwise_fma(e23, c2b, w22[f]);
            }
        }
    }

    // horizontal fold + cross-quad merge (all quads share the same m)
    #pragma unroll
    for (int f = 0; f < 4; f++) {
        float sv = sv2[f].x + sv2[f].y;
        float w0 = w02[f].x + w02[f].y;
        float w1 = w12[f].x + w12[f].y;
        float w2 = w22[f].x + w22[f].y;
        sv += __shfl_xor(sv, 16, 64);  sv += __shfl_xor(sv, 32, 64);
        w0 += __shfl_xor(w0, 16, 64);  w0 += __shfl_xor(w0, 32, 64);
        w1 += __shfl_xor(w1, 16, 64);  w1 += __shfl_xor(w1, 32, 64);
        w2 += __shfl_xor(w2, 16, 64);  w2 += __shfl_xor(w2, 32, 64);
        if (quad == 0) {
            size_t idx = (size_t)split * Q_TOTAL + qbase + f * 16 + col;
            partials[idx]                          = mx[f];
            partials[idx + (size_t)NSPLIT * Q_TOTAL]     = sv;
            partials[idx + (size_t)NSPLIT * Q_TOTAL * 2] = w0;
            partials[idx + (size_t)NSPLIT * Q_TOTAL * 3] = w1;
            partials[idx + (size_t)NSPLIT * Q_TOTAL * 4] = w2;
        }
    }
}

// ---------------------------------------------------------------------------
// Kernel 3: merge NSPLIT partials per query (online, SoA), write output.
// ---------------------------------------------------------------------------
__global__ __launch_bounds__(256) void combine_k(
    const float* __restrict__ x, const float* __restrict__ partials,
    const float* __restrict__ mu_sched, const float* __restrict__ sigma_sched,
    const int* __restrict__ tptr, float* __restrict__ out)
{
    int q = blockIdx.x * 256 + threadIdx.x;   // 0..4095
    int t = tptr[0];
    float mu = mu_sched[t], sg = sigma_sched[t];
    float inv_s2 = 1.0f / (sg * sg);

    const size_t PL = (size_t)NSPLIT * Q_TOTAL;
    float M = -3e38f, S = 0.f, W0 = 0.f, W1 = 0.f, W2 = 0.f;
    for (int sp = 0; sp < NSPLIT; sp++) {
        size_t idx = (size_t)sp * Q_TOTAL + q;
        float mval = partials[idx];
        float sval = partials[idx + PL];
        float w0v  = partials[idx + PL * 2];
        float w1v  = partials[idx + PL * 3];
        float w2v  = partials[idx + PL * 4];
        float mnew = fmaxf(M, mval);
        float sco = fexp2(M - mnew);
        float scn = fexp2(mval - mnew);
        S  = fmaf(S,  sco, sval * scn);
        W0 = fmaf(W0, sco, w0v * scn);
        W1 = fmaf(W1, sco, w1v * scn);
        W2 = fmaf(W2, sco, w2v * scn);
        M = mnew;
    }
    float invS = 1.0f / S;
    int b = q >> 10, rem = q & 1023;
    #pragma unroll
    for (int c = 0; c < 3; c++) {
        float Wc = (c == 0) ? W0 : (c == 1 ? W1 : W2);
        float xc = x[(size_t)b * 3072 + c * 1024 + rem];
        out[(size_t)b * 3072 + c * 1024 + rem] = -(xc - mu * Wc * invS) * inv_s2;
    }
}

extern "C" void kernel_launch(void* const* d_in, const int* in_sizes, int n_in,
                              void* d_out, int out_size, void* d_ws, size_t ws_size,
                              hipStream_t stream) {
    const float* x      = (const float*)d_in[0];
    const float* images = (const float*)d_in[1];
    const float* mu_s   = (const float*)d_in[2];
    const float* sg_s   = (const float*)d_in[3];
    const int*   tptr   = (const int*)d_in[4];
    float* out = (float*)d_out;

    float*    partials = (float*)d_ws;   // 5 planes x 128 x 4096 x 4 B = 10.5 MB
    _Float16* q16      = (_Float16*)((char*)d_ws + (size_t)5 * NSPLIT * Q_TOTAL * 4);

    qbuild_k<<<Q_TOTAL / 256, 256, 0, stream>>>(x, q16);
    score_k<<<GRID, 256, 0, stream>>>(q16, images, mu_s, sg_s, tptr, partials);
    combine_k<<<Q_TOTAL / 256, 256, 0, stream>>>(
        x, partials, mu_s, sg_s, tptr, out);
}

// Round 9
// 113.991 us; speedup vs baseline: 1.0592x; 1.0592x over previous
//
#include <hip/hip_runtime.h>
#include <cstddef>

// Problem constants
#define P_TOTAL 32768            // keys (32 images x 32 x 32)
#define Q_TOTAL 4096             // queries (4 x 32 x 32)
#define NSPLIT 128               // key splits
#define KPS 256                  // keys per split
#define TILES 16                 // 16-key MFMA tiles per split
#define NGROUP 8                 // 32-key PV groups per split
#define QPERWG 256               // queries per workgroup (4 waves x 64)
#define NQG (Q_TOTAL / QPERWG)   // 16 query groups
#define GRID (NSPLIT * NQG)      // 2048 workgroups

// LDS layout (bytes)
#define KEYS_B 16384             // 256 rows x 64 B
#define VT_OFF KEYS_B            // V^T: 4 rows x 528 B + 512 B zero block = 2624
#define VT_PITCH 528
#define VT_ZERO (VT_OFF + 4 * VT_PITCH)
#define P_OFF (VT_OFF + 2624)    // 19008 (16-aligned)
#define P_FRAG 1280              // 16 rows x 80 B
#define P_WAVE (4 * P_FRAG)      // 5120 B per wave
#define LDS_TOTAL (P_OFF + 4 * P_WAVE)   // 39488 B

typedef _Float16 half8 __attribute__((ext_vector_type(8)));
typedef __fp16 fp16x2 __attribute__((ext_vector_type(2)));
typedef __fp16 fp16x4 __attribute__((ext_vector_type(4)));
typedef float floatx4 __attribute__((ext_vector_type(4)));

__device__ __forceinline__ float fexp2(float x) {
#if defined(__has_builtin) && __has_builtin(__builtin_amdgcn_exp2f)
    return __builtin_amdgcn_exp2f(x);
#else
    return exp2f(x);
#endif
}

// ---------------------------------------------------------------------------
// Kernel 1: q16[Q][32] f16 query rows (27 patch vals, 1.0 bias-mate, zeros).
// ---------------------------------------------------------------------------
__global__ __launch_bounds__(256) void qbuild_k(
    const float* __restrict__ x, _Float16* __restrict__ q16)
{
    int q = blockIdx.x * 256 + threadIdx.x;   // 0..4095
    int b = q >> 10, rem = q & 1023, h = rem >> 5, w = rem & 31;
    const float* xb = x + (size_t)b * 3072;
    _Float16 row[32];
    #pragma unroll
    for (int c = 0; c < 3; c++)
      #pragma unroll
      for (int di = 0; di < 3; di++)
        #pragma unroll
        for (int dj = 0; dj < 3; dj++)
            row[c * 9 + di * 3 + dj] =
                (_Float16)xb[c * 1024 + ((h + di + 31) & 31) * 32 + ((w + dj + 31) & 31)];
    row[27] = (_Float16)1.0f;
    row[28] = (_Float16)0.f; row[29] = (_Float16)0.f;
    row[30] = (_Float16)0.f; row[31] = (_Float16)0.f;
    _Float16* qp = q16 + (size_t)q * 32;
    #pragma unroll
    for (int u = 0; u < 4; u++) ((float4*)qp)[u] = ((float4*)row)[u];
}

// ---------------------------------------------------------------------------
// Kernel 2: fused key-build + flash scorer with MFMA PV step.
// Pass 1 (QK, keys-in-A): per-lane max + 2-step cross-quad merge.
// Pass 2: QK again (-m in C) -> e = exp2 -> pkrtz to f16 -> P scratch in
// per-wave LDS (transpose to A layout, m120 pattern) -> PV MFMA against
// V^T = [1, c0, c1, c2] (f16, N=16 with 4 used cols; zero row for col>=4).
// sum_w / weighted centers accumulate entirely in MFMA C — no butterflies.
// Conflict audit: keys XOR-swizzled (0-way); P pitch 80 B (2-way max, free);
// VT pitch 528 B (2-way); P writes b64 cover 32 banks exactly (0-way).
// ---------------------------------------------------------------------------
__global__ __launch_bounds__(256) void score_k(
    const _Float16* __restrict__ q16, const float* __restrict__ images,
    const float* __restrict__ mu_sched, const float* __restrict__ sigma_sched,
    const int* __restrict__ tptr, float* __restrict__ partials)
{
    __shared__ char lds[LDS_TOTAL];
    int tid = threadIdx.x;
    int split = blockIdx.x >> 4;     // 0..127
    int qg    = blockIdx.x & 15;     // 0..15

    int t = tptr[0];
    float mu = mu_sched[t], sg = sigma_sched[t];
    const float LOG2E = 1.4426950408889634f;
    float inv2s2 = 1.0f / (2.0f * sg * sg);
    float s1     = 2.0f * mu * inv2s2 * LOG2E;   // key value scale
    float bscale = -mu * mu * inv2s2 * LOG2E;    // pnorm bias scale

    // ---- Phase 1: build 256 keys into LDS (1 per thread) + VT table ----
    {
        int r = tid;                             // key row 0..255
        int p = split * KPS + r;                 // global key id
        int n = p >> 10, rem = p & 1023, i = rem >> 5, j = rem & 31;
        const float* img = images + (size_t)n * 3072;
        _Float16 hrow[32];
        float pnorm = 0.f, c0 = 0.f, c1 = 0.f, c2 = 0.f;
        #pragma unroll
        for (int c = 0; c < 3; c++)
          #pragma unroll
          for (int di = 0; di < 3; di++)
            #pragma unroll
            for (int dj = 0; dj < 3; dj++) {
                int ii = i + di - 1, jj = j + dj - 1;
                float val = 0.f;
                if (ii >= 0 && ii < 32 && jj >= 0 && jj < 32)
                    val = img[c * 1024 + ii * 32 + jj];
                hrow[c * 9 + di * 3 + dj] = (_Float16)(val * s1);
                pnorm = fmaf(val, val, pnorm);
                if (di == 1 && dj == 1) { if (c == 0) c0 = val; else if (c == 1) c1 = val; else c2 = val; }
            }
        hrow[27] = (_Float16)(pnorm * bscale);
        hrow[28] = (_Float16)0.f; hrow[29] = (_Float16)0.f;
        hrow[30] = (_Float16)0.f; hrow[31] = (_Float16)0.f;
        int sw = (r >> 1) & 3;                   // 16B-chunk XOR swizzle
        float4* src4 = (float4*)hrow;
        #pragma unroll
        for (int c = 0; c < 4; c++)
            *(float4*)(lds + r * 64 + ((c ^ sw) << 4)) = src4[c];
        // VT rows: [1.0, c0, c1, c2] per key (f16)
        _Float16* vt = (_Float16*)(lds + VT_OFF);
        vt[0 * (VT_PITCH / 2) + r] = (_Float16)1.0f;
        vt[1 * (VT_PITCH / 2) + r] = (_Float16)c0;
        vt[2 * (VT_PITCH / 2) + r] = (_Float16)c1;
        vt[3 * (VT_PITCH / 2) + r] = (_Float16)c2;
        if (tid < 128) ((float*)(lds + VT_ZERO))[tid] = 0.f;   // zero block 512 B
    }

    // ---- B-fragments: queries from q16 (global, L2-hot) ----
    int lane = tid & 63, wid = tid >> 6;
    int col  = lane & 15, quad = lane >> 4;
    int qbase = qg * QPERWG + wid * 64;

    half8 qf[4];
    #pragma unroll
    for (int f = 0; f < 4; f++)
        qf[f] = *(const half8*)(q16 + (size_t)(qbase + f * 16 + col) * 32 + quad * 8);
    __syncthreads();

    int swc = (col >> 1) & 3;
    const char* abase = lds + col * 64 + ((quad ^ swc) << 4);   // QK A: key row = tile*16+col

    // ---- Pass 1: per-lane max over this lane's keys ----
    float mx[4];
    {
        floatx4 mv[4];
        #pragma unroll
        for (int f = 0; f < 4; f++) mv[f] = (floatx4){-3e38f, -3e38f, -3e38f, -3e38f};
        #pragma unroll 4
        for (int tile = 0; tile < TILES; tile++) {
            half8 ak = *(const half8*)(abase + tile * 1024);
            #pragma unroll
            for (int f = 0; f < 4; f++) {
                floatx4 a = __builtin_amdgcn_mfma_f32_16x16x32_f16(
                    ak, qf[f], (floatx4){0.f, 0.f, 0.f, 0.f}, 0, 0, 0);
                mv[f] = __builtin_elementwise_max(mv[f], a);
            }
        }
        #pragma unroll
        for (int f = 0; f < 4; f++) {
            mx[f] = fmaxf(fmaxf(mv[f][0], mv[f][1]), fmaxf(mv[f][2], mv[f][3]));
            mx[f] = fmaxf(mx[f], __shfl_xor(mx[f], 16, 64));
            mx[f] = fmaxf(mx[f], __shfl_xor(mx[f], 32, 64));
        }
    }
    floatx4 nmv[4];
    #pragma unroll
    for (int f = 0; f < 4; f++)
        nmv[f] = (floatx4){-mx[f], -mx[f], -mx[f], -mx[f]};

    // write m-plane (each lane of quad 0 holds m for query f*16+col)
    if (quad == 0) {
        #pragma unroll
        for (int f = 0; f < 4; f++)
            partials[(size_t)split * Q_TOTAL + qbase + f * 16 + col] = mx[f];
    }

    // ---- Pass 2: QK -> exp2 -> f16 P scratch -> PV MFMA ----
    const char* pwave = lds + P_OFF + wid * P_WAVE;
    char* pwbase = (char*)pwave + col * 80 + quad * 8;       // write: row=q(col), key off
    const char* prbase = pwave + col * 80 + quad * 16;       // read: A[m=col][k=quad*8+j]
    const char* vbase = lds + VT_OFF + (col < 4 ? col * VT_PITCH : 4 * VT_PITCH)
                        + quad * 16;                         // VT row / zero block

    floatx4 acc[4];
    #pragma unroll
    for (int f = 0; f < 4; f++) acc[f] = (floatx4){0.f, 0.f, 0.f, 0.f};

    for (int g = 0; g < NGROUP; g++) {
        half8 ak0 = *(const half8*)(abase + (2 * g) * 1024);
        half8 ak1 = *(const half8*)(abase + (2 * g + 1) * 1024);
        half8 vb  = *(const half8*)(vbase + g * 64);
        #pragma unroll
        for (int f = 0; f < 4; f++) {
            floatx4 a0 = __builtin_amdgcn_mfma_f32_16x16x32_f16(ak0, qf[f], nmv[f], 0, 0, 0);
            floatx4 a1 = __builtin_amdgcn_mfma_f32_16x16x32_f16(ak1, qf[f], nmv[f], 0, 0, 0);
            fp16x2 p00 = __builtin_amdgcn_cvt_pkrtz(fexp2(a0[0]), fexp2(a0[1]));
            fp16x2 p01 = __builtin_amdgcn_cvt_pkrtz(fexp2(a0[2]), fexp2(a0[3]));
            fp16x2 p10 = __builtin_amdgcn_cvt_pkrtz(fexp2(a1[0]), fexp2(a1[1]));
            fp16x2 p11 = __builtin_amdgcn_cvt_pkrtz(fexp2(a1[2]), fexp2(a1[3]));
            fp16x4 w0 = __builtin_shufflevector(p00, p01, 0, 1, 2, 3);
            fp16x4 w1 = __builtin_shufflevector(p10, p11, 0, 1, 2, 3);
            *(fp16x4*)(pwbase + f * P_FRAG)      = w0;   // tile 2g   keys
            *(fp16x4*)(pwbase + f * P_FRAG + 32) = w1;   // tile 2g+1 keys
        }
        #pragma unroll
        for (int f = 0; f < 4; f++) {
            half8 pa = *(const half8*)(prbase + f * P_FRAG);
            acc[f] = __builtin_amdgcn_mfma_f32_16x16x32_f16(pa, vb, acc[f], 0, 0, 0);
        }
    }

    // ---- store: lane(col<4, quad) holds component col for queries quad*4+r ----
    if (col < 4) {
        const size_t PL = (size_t)NSPLIT * Q_TOTAL;
        float* plane = partials + (size_t)(col + 1) * PL + (size_t)split * Q_TOTAL;
        #pragma unroll
        for (int f = 0; f < 4; f++)
            #pragma unroll
            for (int r = 0; r < 4; r++)
                plane[qbase + f * 16 + quad * 4 + r] = acc[f][r];
    }
}

// ---------------------------------------------------------------------------
// Kernel 3: merge NSPLIT partials per query (online, SoA), write output.
// ---------------------------------------------------------------------------
__global__ __launch_bounds__(256) void combine_k(
    const float* __restrict__ x, const float* __restrict__ partials,
    const float* __restrict__ mu_sched, const float* __restrict__ sigma_sched,
    const int* __restrict__ tptr, float* __restrict__ out)
{
    int q = blockIdx.x * 256 + threadIdx.x;   // 0..4095
    int t = tptr[0];
    float mu = mu_sched[t], sg = sigma_sched[t];
    float inv_s2 = 1.0f / (sg * sg);

    const size_t PL = (size_t)NSPLIT * Q_TOTAL;
    float M = -3e38f, S = 0.f, W0 = 0.f, W1 = 0.f, W2 = 0.f;
    for (int sp = 0; sp < NSPLIT; sp++) {
        size_t idx = (size_t)sp * Q_TOTAL + q;
        float mval = partials[idx];
        float sval = partials[idx + PL];
        float w0v  = partials[idx + PL * 2];
        float w1v  = partials[idx + PL * 3];
        float w2v  = partials[idx + PL * 4];
        float mnew = fmaxf(M, mval);
        float sco = fexp2(M - mnew);
        float scn = fexp2(mval - mnew);
        S  = fmaf(S,  sco, sval * scn);
        W0 = fmaf(W0, sco, w0v * scn);
        W1 = fmaf(W1, sco, w1v * scn);
        W2 = fmaf(W2, sco, w2v * scn);
        M = mnew;
    }
    float invS = 1.0f / S;
    int b = q >> 10, rem = q & 1023;
    #pragma unroll
    for (int c = 0; c < 3; c++) {
        float Wc = (c == 0) ? W0 : (c == 1 ? W1 : W2);
        float xc = x[(size_t)b * 3072 + c * 1024 + rem];
        out[(size_t)b * 3072 + c * 1024 + rem] = -(xc - mu * Wc * invS) * inv_s2;
    }
}

extern "C" void kernel_launch(void* const* d_in, const int* in_sizes, int n_in,
                              void* d_out, int out_size, void* d_ws, size_t ws_size,
                              hipStream_t stream) {
    const float* x      = (const float*)d_in[0];
    const float* images = (const float*)d_in[1];
    const float* mu_s   = (const float*)d_in[2];
    const float* sg_s   = (const float*)d_in[3];
    const int*   tptr   = (const int*)d_in[4];
    float* out = (float*)d_out;

    float*    partials = (float*)d_ws;   // 5 planes x 128 x 4096 x 4 B = 10.5 MB
    _Float16* q16      = (_Float16*)((char*)d_ws + (size_t)5 * NSPLIT * Q_TOTAL * 4);

    qbuild_k<<<Q_TOTAL / 256, 256, 0, stream>>>(x, q16);
    score_k<<<GRID, 256, 0, stream>>>(q16, images, mu_s, sg_s, tptr, partials);
    combine_k<<<Q_TOTAL / 256, 256, 0, stream>>>(
        x, partials, mu_s, sg_s, tptr, out);
}

// Round 10
// 110.881 us; speedup vs baseline: 1.0890x; 1.0281x over previous
//
#include <hip/hip_runtime.h>
#include <cstddef>

// Problem constants
#define P_TOTAL 32768            // keys (32 images x 32 x 32)
#define Q_TOTAL 4096             // queries (4 x 32 x 32)
#define NSPLIT 128               // key splits
#define KPS 256                  // keys per split
#define TILES 16                 // 16-key MFMA tiles per split
#define NGROUP 8                 // 32-key (tile-pair) PV groups per split
#define QPERWG 256               // queries per workgroup (4 waves x 64)
#define NQG (Q_TOTAL / QPERWG)   // 16 query groups
#define GRID (NSPLIT * NQG)      // 2048 workgroups

// LDS layout (bytes)
#define KEYS_B 16384             // 256 rows x 64 B
#define VT_OFF KEYS_B            // V^T: 4 rows x 528 B (kk-ordered)
#define VT_PITCH 528
#define LDS_TOTAL (VT_OFF + 4 * VT_PITCH)   // 18496 B -> LDS allows 8 wg/CU

typedef _Float16 half8 __attribute__((ext_vector_type(8)));
typedef __fp16 fp16x2 __attribute__((ext_vector_type(2)));
typedef __fp16 fp16x4 __attribute__((ext_vector_type(4)));
typedef __fp16 fp16x8 __attribute__((ext_vector_type(8)));
typedef float floatx4 __attribute__((ext_vector_type(4)));

union h8cast { fp16x8 a; half8 b; };

__device__ __forceinline__ float fexp2(float x) {
#if defined(__has_builtin) && __has_builtin(__builtin_amdgcn_exp2f)
    return __builtin_amdgcn_exp2f(x);
#else
    return exp2f(x);
#endif
}

// ---------------------------------------------------------------------------
// Kernel 1: q16[Q][32] f16 query rows (27 patch vals, 1.0 bias-mate, zeros).
// ---------------------------------------------------------------------------
__global__ __launch_bounds__(256) void qbuild_k(
    const float* __restrict__ x, _Float16* __restrict__ q16)
{
    int q = blockIdx.x * 256 + threadIdx.x;   // 0..4095
    int b = q >> 10, rem = q & 1023, h = rem >> 5, w = rem & 31;
    const float* xb = x + (size_t)b * 3072;
    _Float16 row[32];
    #pragma unroll
    for (int c = 0; c < 3; c++)
      #pragma unroll
      for (int di = 0; di < 3; di++)
        #pragma unroll
        for (int dj = 0; dj < 3; dj++)
            row[c * 9 + di * 3 + dj] =
                (_Float16)xb[c * 1024 + ((h + di + 31) & 31) * 32 + ((w + dj + 31) & 31)];
    row[27] = (_Float16)1.0f;
    row[28] = (_Float16)0.f; row[29] = (_Float16)0.f;
    row[30] = (_Float16)0.f; row[31] = (_Float16)0.f;
    _Float16* qp = q16 + (size_t)q * 32;
    #pragma unroll
    for (int u = 0; u < 4; u++) ((float4*)qp)[u] = ((float4*)row)[u];
}

// ---------------------------------------------------------------------------
// Kernel 2: fused key-build + flash scorer, ZERO-COPY P path.
// Key row permutation at build time: LDS row (tp, t, m) holds global key
// kk = tp*32 + (m>>2)*8 + t*4 + (m&3).  Then QK D (lane(c,q) reg r =
// D[row 4q+r][col c]) delivers, over a tile pair, exactly the PV B-operand
// (lane(c,q) half j = B[k=8q+j][n=c]) after exp2+pkrtz — no LDS round-trip.
// PV: A = V^T rows [1, c0, c1, c2] (kk-ordered, cols>=4 are register zeros),
// acc D[m=comp][n=query]; quad-0 lanes hold all 4 components per query.
// Pass 1: per-lane max + 2-shuffle cross-quad merge.  Pass 2: -m in QK C.
// ---------------------------------------------------------------------------
__global__ __launch_bounds__(256) void score_k(
    const _Float16* __restrict__ q16, const float* __restrict__ images,
    const float* __restrict__ mu_sched, const float* __restrict__ sigma_sched,
    const int* __restrict__ tptr, float* __restrict__ partials)
{
    __shared__ char lds[LDS_TOTAL];
    int tid = threadIdx.x;
    int split = blockIdx.x >> 4;     // 0..127
    int qg    = blockIdx.x & 15;     // 0..15

    int t = tptr[0];
    float mu = mu_sched[t], sg = sigma_sched[t];
    const float LOG2E = 1.4426950408889634f;
    float inv2s2 = 1.0f / (2.0f * sg * sg);
    float s1     = 2.0f * mu * inv2s2 * LOG2E;   // key value scale
    float bscale = -mu * mu * inv2s2 * LOG2E;    // pnorm bias scale

    // ---- Phase 1: build 256 keys into LDS (permuted rows) + VT table ----
    {
        int r = tid;                             // LDS key row 0..255
        int m16 = r & 15, tt = (r >> 4) & 1, tp = r >> 5;
        int kk = tp * 32 + (m16 >> 2) * 8 + tt * 4 + (m16 & 3);  // global-in-split key
        int p = split * KPS + kk;
        int n = p >> 10, rem = p & 1023, i = rem >> 5, j = rem & 31;
        const float* img = images + (size_t)n * 3072;
        _Float16 hrow[32];
        float pnorm = 0.f, c0 = 0.f, c1 = 0.f, c2 = 0.f;
        #pragma unroll
        for (int c = 0; c < 3; c++)
          #pragma unroll
          for (int di = 0; di < 3; di++)
            #pragma unroll
            for (int dj = 0; dj < 3; dj++) {
                int ii = i + di - 1, jj = j + dj - 1;
                float val = 0.f;
                if (ii >= 0 && ii < 32 && jj >= 0 && jj < 32)
                    val = img[c * 1024 + ii * 32 + jj];
                hrow[c * 9 + di * 3 + dj] = (_Float16)(val * s1);
                pnorm = fmaf(val, val, pnorm);
                if (di == 1 && dj == 1) { if (c == 0) c0 = val; else if (c == 1) c1 = val; else c2 = val; }
            }
        hrow[27] = (_Float16)(pnorm * bscale);
        hrow[28] = (_Float16)0.f; hrow[29] = (_Float16)0.f;
        hrow[30] = (_Float16)0.f; hrow[31] = (_Float16)0.f;
        int sw = (r >> 1) & 3;                   // 16B-chunk XOR swizzle
        float4* src4 = (float4*)hrow;
        #pragma unroll
        for (int c = 0; c < 4; c++)
            *(float4*)(lds + r * 64 + ((c ^ sw) << 4)) = src4[c];
        // VT rows (kk-indexed): [1, c0, c1, c2]
        _Float16* vt = (_Float16*)(lds + VT_OFF);
        vt[0 * (VT_PITCH / 2) + kk] = (_Float16)1.0f;
        vt[1 * (VT_PITCH / 2) + kk] = (_Float16)c0;
        vt[2 * (VT_PITCH / 2) + kk] = (_Float16)c1;
        vt[3 * (VT_PITCH / 2) + kk] = (_Float16)c2;
    }

    // ---- B-fragments: queries from q16 (global, L2-hot) ----
    int lane = tid & 63, wid = tid >> 6;
    int col  = lane & 15, quad = lane >> 4;
    int qbase = qg * QPERWG + wid * 64;

    half8 qf[4];
    #pragma unroll
    for (int f = 0; f < 4; f++)
        qf[f] = *(const half8*)(q16 + (size_t)(qbase + f * 16 + col) * 32 + quad * 8);
    __syncthreads();

    int swc = (col >> 1) & 3;
    const char* abase = lds + col * 64 + ((quad ^ swc) << 4);   // QK A tile reads

    // ---- Pass 1: per-lane max over this lane's keys ----
    float mx[4];
    {
        floatx4 mv[4];
        #pragma unroll
        for (int f = 0; f < 4; f++) mv[f] = (floatx4){-3e38f, -3e38f, -3e38f, -3e38f};
        #pragma unroll 4
        for (int tile = 0; tile < TILES; tile++) {
            half8 ak = *(const half8*)(abase + tile * 1024);
            #pragma unroll
            for (int f = 0; f < 4; f++) {
                floatx4 a = __builtin_amdgcn_mfma_f32_16x16x32_f16(
                    ak, qf[f], (floatx4){0.f, 0.f, 0.f, 0.f}, 0, 0, 0);
                mv[f] = __builtin_elementwise_max(mv[f], a);
            }
        }
        #pragma unroll
        for (int f = 0; f < 4; f++) {
            mx[f] = fmaxf(fmaxf(mv[f][0], mv[f][1]), fmaxf(mv[f][2], mv[f][3]));
            mx[f] = fmaxf(mx[f], __shfl_xor(mx[f], 16, 64));
            mx[f] = fmaxf(mx[f], __shfl_xor(mx[f], 32, 64));
        }
    }
    floatx4 nmv[4];
    #pragma unroll
    for (int f = 0; f < 4; f++)
        nmv[f] = (floatx4){-mx[f], -mx[f], -mx[f], -mx[f]};

    // write m-plane (quad-0 lanes own query f*16+col)
    if (quad == 0) {
        #pragma unroll
        for (int f = 0; f < 4; f++)
            partials[(size_t)split * Q_TOTAL + qbase + f * 16 + col] = mx[f];
    }

    // ---- Pass 2: QK (-m in C) -> exp2 -> pkrtz -> PV MFMA, no LDS hop ----
    const char* vrow = lds + VT_OFF + col * VT_PITCH;   // valid for col<4
    floatx4 acc[4];
    #pragma unroll
    for (int f = 0; f < 4; f++) acc[f] = (floatx4){0.f, 0.f, 0.f, 0.f};

    #pragma unroll 2
    for (int g = 0; g < NGROUP; g++) {
        half8 ak0 = *(const half8*)(abase + (2 * g) * 1024);
        half8 ak1 = *(const half8*)(abase + (2 * g + 1) * 1024);
        // A operand = V^T fragment: lane(col,quad) = VT[col][g*32 + quad*8 .. +7]
        half8 av = (half8)(_Float16)0.f;
        if (col < 4) av = *(const half8*)(vrow + g * 64 + quad * 16);
        #pragma unroll
        for (int f = 0; f < 4; f++) {
            floatx4 a0 = __builtin_amdgcn_mfma_f32_16x16x32_f16(ak0, qf[f], nmv[f], 0, 0, 0);
            floatx4 a1 = __builtin_amdgcn_mfma_f32_16x16x32_f16(ak1, qf[f], nmv[f], 0, 0, 0);
            fp16x2 p00 = __builtin_amdgcn_cvt_pkrtz(fexp2(a0[0]), fexp2(a0[1]));
            fp16x2 p01 = __builtin_amdgcn_cvt_pkrtz(fexp2(a0[2]), fexp2(a0[3]));
            fp16x2 p10 = __builtin_amdgcn_cvt_pkrtz(fexp2(a1[0]), fexp2(a1[1]));
            fp16x2 p11 = __builtin_amdgcn_cvt_pkrtz(fexp2(a1[2]), fexp2(a1[3]));
            fp16x4 lo = __builtin_shufflevector(p00, p01, 0, 1, 2, 3);
            fp16x4 hi = __builtin_shufflevector(p10, p11, 0, 1, 2, 3);
            h8cast u; u.a = __builtin_shufflevector(lo, hi, 0, 1, 2, 3, 4, 5, 6, 7);
            acc[f] = __builtin_amdgcn_mfma_f32_16x16x32_f16(av, u.b, acc[f], 0, 0, 0);
        }
    }

    // ---- store: quad-0 lane holds comps [sum,w0,w1,w2] for query f*16+col ----
    if (quad == 0) {
        const size_t PL = (size_t)NSPLIT * Q_TOTAL;
        #pragma unroll
        for (int f = 0; f < 4; f++) {
            size_t idx = (size_t)split * Q_TOTAL + qbase + f * 16 + col;
            partials[idx + PL]     = acc[f][0];
            partials[idx + PL * 2] = acc[f][1];
            partials[idx + PL * 3] = acc[f][2];
            partials[idx + PL * 4] = acc[f][3];
        }
    }
}

// ---------------------------------------------------------------------------
// Kernel 3: merge NSPLIT partials per query (two independent online chains
// to break the serial max/exp dependency), write output.
// ---------------------------------------------------------------------------
__global__ __launch_bounds__(256) void combine_k(
    const float* __restrict__ x, const float* __restrict__ partials,
    const float* __restrict__ mu_sched, const float* __restrict__ sigma_sched,
    const int* __restrict__ tptr, float* __restrict__ out)
{
    int q = blockIdx.x * 256 + threadIdx.x;   // 0..4095
    int t = tptr[0];
    float mu = mu_sched[t], sg = sigma_sched[t];
    float inv_s2 = 1.0f / (sg * sg);

    const size_t PL = (size_t)NSPLIT * Q_TOTAL;
    float M1 = -3e38f, S1 = 0.f, A1 = 0.f, B1 = 0.f, C1 = 0.f;
    float M2 = -3e38f, S2 = 0.f, A2 = 0.f, B2 = 0.f, C2 = 0.f;
    #pragma unroll 4
    for (int sp = 0; sp < NSPLIT / 2; sp++) {
        {
            size_t idx = (size_t)sp * Q_TOTAL + q;
            float mval = partials[idx];
            float mnew = fmaxf(M1, mval);
            float sco = fexp2(M1 - mnew), scn = fexp2(mval - mnew);
            S1 = fmaf(S1, sco, partials[idx + PL] * scn);
            A1 = fmaf(A1, sco, partials[idx + PL * 2] * scn);
            B1 = fmaf(B1, sco, partials[idx + PL * 3] * scn);
            C1 = fmaf(C1, sco, partials[idx + PL * 4] * scn);
            M1 = mnew;
        }
        {
            size_t idx = (size_t)(sp + NSPLIT / 2) * Q_TOTAL + q;
            float mval = partials[idx];
            float mnew = fmaxf(M2, mval);
            float sco = fexp2(M2 - mnew), scn = fexp2(mval - mnew);
            S2 = fmaf(S2, sco, partials[idx + PL] * scn);
            A2 = fmaf(A2, sco, partials[idx + PL * 2] * scn);
            B2 = fmaf(B2, sco, partials[idx + PL * 3] * scn);
            C2 = fmaf(C2, sco, partials[idx + PL * 4] * scn);
            M2 = mnew;
        }
    }
    float M = fmaxf(M1, M2);
    float r1 = fexp2(M1 - M), r2 = fexp2(M2 - M);
    float S  = S1 * r1 + S2 * r2;
    float W0 = A1 * r1 + A2 * r2;
    float W1 = B1 * r1 + B2 * r2;
    float W2 = C1 * r1 + C2 * r2;

    float invS = 1.0f / S;
    int b = q >> 10, rem = q & 1023;
    #pragma unroll
    for (int c = 0; c < 3; c++) {
        float Wc = (c == 0) ? W0 : (c == 1 ? W1 : W2);
        float xc = x[(size_t)b * 3072 + c * 1024 + rem];
        out[(size_t)b * 3072 + c * 1024 + rem] = -(xc - mu * Wc * invS) * inv_s2;
    }
}

extern "C" void kernel_launch(void* const* d_in, const int* in_sizes, int n_in,
                              void* d_out, int out_size, void* d_ws, size_t ws_size,
                              hipStream_t stream) {
    const float* x      = (const float*)d_in[0];
    const float* images = (const float*)d_in[1];
    const float* mu_s   = (const float*)d_in[2];
    const float* sg_s   = (const float*)d_in[3];
    const int*   tptr   = (const int*)d_in[4];
    float* out = (float*)d_out;

    float*    partials = (float*)d_ws;   // 5 planes x 128 x 4096 x 4 B = 10.5 MB
    _Float16* q16      = (_Float16*)((char*)d_ws + (size_t)5 * NSPLIT * Q_TOTAL * 4);

    qbuild_k<<<Q_TOTAL / 256, 256, 0, stream>>>(x, q16);
    score_k<<<GRID, 256, 0, stream>>>(q16, images, mu_s, sg_s, tptr, partials);
    combine_k<<<Q_TOTAL / 256, 256, 0, stream>>>(
        x, partials, mu_s, sg_s, tptr, out);
}